// Round 1
// baseline (464.688 us; speedup 1.0000x reference)
//
#include <hip/hip_runtime.h>

// Problem constants (from reference): grid (1,4,1024,1024) f32,
// out (1,4,4096,4096) f32, coordinate_start int32[2] in [0,512).
constexpr int C    = 4;
constexpr int GH   = 1024;
constexpr int GW   = 1024;
constexpr int HOUT = 4096;
constexpr int WOUT = 4096;

// offset_h = offset_w = (1024-1)/2 = 511.5
// coord = (m - 511.5)/511.5 ; x = (coord+1)*0.5*1023  ==  m (up to fp32 rounding)
// -> bilinear weights are ~0/~1; we still do the full bilinear in fp32 to
//    track the reference's rounding. Reciprocal-multiply instead of divide:
//    shifts x by <~1e-4 which changes the result by ~2e-6 << 6.2e-5 threshold.

__global__ __launch_bounds__(256) void grid_sample_k(
    const float* __restrict__ grid,
    const int*   __restrict__ cstart,
    float4*      __restrict__ out4)
{
    const int tid = blockIdx.x * blockDim.x + threadIdx.x;
    // tid -> (c, oh, ow4); WOUT/4 = 1024 float4's per row
    const int ow4 = tid & 1023;
    const int r   = tid >> 10;
    const int oh  = r & (HOUT - 1);
    const int c   = r >> 12;

    const int sx = cstart[0];
    const int sy = cstart[1];

    constexpr float kInvOff = 1.0f / 511.5f;

    // y depends only on oh — one computation per thread
    const int my = (sy + oh) & (GH - 1);
    const float fy = ((float)my - 511.5f) * kInvOff;
    float y = (fy + 1.0f) * 0.5f * (float)(GH - 1);
    y = fminf(fmaxf(y, 0.0f), (float)(GH - 1));
    const float y0f = floorf(y);
    const float wy  = y - y0f;
    const int   y0  = (int)y0f;
    const int   y1  = min(y0 + 1, GH - 1);

    const float* __restrict__ gp   = grid + (size_t)c * (GH * GW);
    const float* __restrict__ row0 = gp + (size_t)y0 * GW;
    const float* __restrict__ row1 = gp + (size_t)y1 * GW;

    const int owbase = ow4 << 2;
    float res[4];
#pragma unroll
    for (int i = 0; i < 4; ++i) {
        const int mx = (sx + owbase + i) & (GW - 1);
        const float fx = ((float)mx - 511.5f) * kInvOff;
        float x = (fx + 1.0f) * 0.5f * (float)(GW - 1);
        x = fminf(fmaxf(x, 0.0f), (float)(GW - 1));
        const float x0f = floorf(x);
        const float wx  = x - x0f;
        const int   x0  = (int)x0f;
        const int   x1  = min(x0 + 1, GW - 1);

        const float v00 = row0[x0];
        const float v01 = row0[x1];
        const float v10 = row1[x0];
        const float v11 = row1[x1];

        const float top = v00 * (1.0f - wx) + v01 * wx;
        const float bot = v10 * (1.0f - wx) + v11 * wx;
        res[i] = top * (1.0f - wy) + bot * wy;
    }

    out4[tid] = make_float4(res[0], res[1], res[2], res[3]);
}

extern "C" void kernel_launch(void* const* d_in, const int* in_sizes, int n_in,
                              void* d_out, int out_size, void* d_ws, size_t ws_size,
                              hipStream_t stream)
{
    const float* grid   = (const float*)d_in[0];
    const int*   cstart = (const int*)d_in[1];
    // d_in[2..5] are h, w, support_resolution_h, support_resolution_w — fixed
    // at 4096/4096/1024/1024 per the reference module; baked in as constexpr.
    float4* out = (float4*)d_out;

    const int total4 = C * HOUT * (WOUT / 4);  // 16,777,216 float4 stores
    const int block  = 256;
    const int nblk   = total4 / block;         // 65,536 blocks
    grid_sample_k<<<nblk, block, 0, stream>>>(grid, cstart, out);
}